// Round 4
// baseline (2123.854 us; speedup 1.0000x reference)
//
#include <hip/hip_runtime.h>
#include <hip/hip_bf16.h>

// ---------- helpers ----------
__device__ __forceinline__ float bf2f(unsigned short u) {
    union { unsigned int i; float f; } v;
    v.i = ((unsigned int)u) << 16;
    return v.f;
}
__device__ __forceinline__ unsigned short f2bf(float f) {
    __hip_bfloat16 h = __float2bfloat16(f);   // RNE
    return *reinterpret_cast<unsigned short*>(&h);
}

// ---------- dtype probe: flag=0 -> bf16 inputs, flag=1 -> f32 inputs ----------
// True bf16 N(0,1) data: exponent field <= ~0x82 always -> wild==0.
// f32 data read as ushorts: half the samples are random mantissa bits ->
// ~25% have exponent >= 0xC0 -> wild >> 0.
__global__ void probe_dtype(const unsigned short* __restrict__ x, int* flag) {
    if (blockIdx.x == 0 && threadIdx.x == 0) {
        int wild = 0;
        for (int i = 0; i < 512; ++i) {
            unsigned e = (x[i] >> 7) & 0xFF;
            if (e >= 0xC0) ++wild;
        }
        *flag = (wild > 0) ? 1 : 0;
    }
}

// ---------- COO scatter in ORIGINAL feature space ----------
// acc[rows[e]-r0] += vals[e] * x[cols[e]]   for rows[e] in [r0, r1)
// blockDim = (64,4): one 64-lane wave per edge, lane = channel.
__global__ __launch_bounds__(256) void scatter_x(
    const int* __restrict__ rows, const int* __restrict__ cols,
    const void* __restrict__ vals, const void* __restrict__ x,
    const int* __restrict__ flag,
    float* __restrict__ acc, int nnz, int r0, int r1)
{
    int e = blockIdx.x * 4 + threadIdx.y;
    if (e >= nnz) return;
    int r = rows[e];
    if (r < r0 || r >= r1) return;
    int c = threadIdx.x;
    int cc = cols[e];
    const int fl = *flag;
    float v, xv;
    if (fl) {
        v  = ((const float*)vals)[e];
        xv = ((const float*)x)[(size_t)cc * 64 + c];
    } else {
        v  = bf2f(((const unsigned short*)vals)[e]);
        xv = bf2f(((const unsigned short*)x)[(size_t)cc * 64 + c]);
    }
    atomicAdd(&acc[(size_t)(r - r0) * 64 + c], v * xv);
}

// ---------- phase GEMM: T = acc_chunk @ W  (64x64 W), epilogue by mode ----------
// mode 0: m[g] = relu(T * cci[g])        (first phase, overwrite)
// mode 1: m[g] += relu(T)                (later phases, accumulate)
// m lives inside d_out at element offset mbase (bf16 or f32 per flag).
__global__ __launch_bounds__(256) void gemm_phase(
    const float* __restrict__ acc,       // [n_rows x 64], local to chunk
    const void* __restrict__ W,          // 64x64
    const void* __restrict__ cci,        // rank cci base (mode 0 only)
    void* mout,                          // d_out base
    const int* __restrict__ flag,
    int n_rows, long long grow0, long long mbase, int mode)
{
    __shared__ float Ws[64][64];
    __shared__ float xs[64][65];
    const int tid = threadIdx.x;
    const int tx = tid & 15, ty = tid >> 4;
    const int fl = *flag;

    if (fl) {
        const float* Wf = (const float*)W;
        for (int i = tid; i < 4096; i += 256) Ws[i >> 6][i & 63] = Wf[i];
    } else {
        const unsigned short* Wb = (const unsigned short*)W;
        for (int i = tid; i < 4096; i += 256) Ws[i >> 6][i & 63] = bf2f(Wb[i]);
    }
    const int lrow0 = blockIdx.x * 64;
    for (int i = tid; i < 4096; i += 256) {
        int r = i >> 6, c = i & 63;
        int l = lrow0 + r;
        xs[r][c] = (l < n_rows) ? acc[(size_t)l * 64 + c] : 0.f;
    }
    __syncthreads();

    float a4[4][4];
#pragma unroll
    for (int a = 0; a < 4; ++a)
#pragma unroll
        for (int b = 0; b < 4; ++b) a4[a][b] = 0.f;

#pragma unroll 8
    for (int k = 0; k < 64; ++k) {
        float4 w4 = *reinterpret_cast<const float4*>(&Ws[k][tx << 2]);
#pragma unroll
        for (int rr = 0; rr < 4; ++rr) {
            float xv = xs[ty + 16 * rr][k];
            a4[rr][0] += xv * w4.x;
            a4[rr][1] += xv * w4.y;
            a4[rr][2] += xv * w4.z;
            a4[rr][3] += xv * w4.w;
        }
    }

#pragma unroll
    for (int rr = 0; rr < 4; ++rr) {
        int l = lrow0 + ty + 16 * rr;
        if (l >= n_rows) continue;
        long long g = grow0 + l;                       // row within rank
        size_t co = (size_t)g * 64 + (tx << 2);        // cci element offset
        size_t ob = (size_t)mbase + co;                // m element offset
        float t[4] = { a4[rr][0], a4[rr][1], a4[rr][2], a4[rr][3] };
        if (mode == 0) {
            float c4[4];
            if (fl) {
                float4 cv = *reinterpret_cast<const float4*>(&((const float*)cci)[co]);
                c4[0] = cv.x; c4[1] = cv.y; c4[2] = cv.z; c4[3] = cv.w;
            } else {
                ushort4 cv = *reinterpret_cast<const ushort4*>(&((const unsigned short*)cci)[co]);
                c4[0] = bf2f(cv.x); c4[1] = bf2f(cv.y); c4[2] = bf2f(cv.z); c4[3] = bf2f(cv.w);
            }
#pragma unroll
            for (int j = 0; j < 4; ++j) t[j] = fmaxf(t[j] * c4[j], 0.f);
            if (fl) {
                float4 o; o.x = t[0]; o.y = t[1]; o.z = t[2]; o.w = t[3];
                *reinterpret_cast<float4*>(&((float*)mout)[ob]) = o;
            } else {
                ushort4 o; o.x = f2bf(t[0]); o.y = f2bf(t[1]); o.z = f2bf(t[2]); o.w = f2bf(t[3]);
                *reinterpret_cast<ushort4*>(&((unsigned short*)mout)[ob]) = o;
            }
        } else {
            if (fl) {
                float* mp = (float*)mout;
                float4 ov = *reinterpret_cast<const float4*>(&mp[ob]);
                float4 o;
                o.x = ov.x + fmaxf(t[0], 0.f);
                o.y = ov.y + fmaxf(t[1], 0.f);
                o.z = ov.z + fmaxf(t[2], 0.f);
                o.w = ov.w + fmaxf(t[3], 0.f);
                *reinterpret_cast<float4*>(&mp[ob]) = o;
            } else {
                unsigned short* mp = (unsigned short*)mout;
                ushort4 ov = *reinterpret_cast<const ushort4*>(&mp[ob]);
                ushort4 o;
                o.x = f2bf(bf2f(ov.x) + fmaxf(t[0], 0.f));
                o.y = f2bf(bf2f(ov.y) + fmaxf(t[1], 0.f));
                o.z = f2bf(bf2f(ov.z) + fmaxf(t[2], 0.f));
                o.w = f2bf(bf2f(ov.w) + fmaxf(t[3], 0.f));
                *reinterpret_cast<ushort4*>(&mp[ob]) = o;
            }
        }
    }
}

// ---------- finalize: out = relu(m @ Wg). m aliases out (same rows, LDS-staged) ----------
__global__ __launch_bounds__(256) void finalize(
    void* mout, const void* __restrict__ Wg, const int* __restrict__ flag,
    int N, long long mbase)
{
    __shared__ float Ws[64][64];
    __shared__ float ms[64][65];
    const int tid = threadIdx.x;
    const int tx = tid & 15, ty = tid >> 4;
    const int fl = *flag;

    if (fl) {
        const float* Wf = (const float*)Wg;
        for (int i = tid; i < 4096; i += 256) Ws[i >> 6][i & 63] = Wf[i];
    } else {
        const unsigned short* Wb = (const unsigned short*)Wg;
        for (int i = tid; i < 4096; i += 256) Ws[i >> 6][i & 63] = bf2f(Wb[i]);
    }
    const int row0 = blockIdx.x * 64;
    for (int i = tid; i < 4096; i += 256) {
        int r = i >> 6, c = i & 63;
        int g = row0 + r;
        float v = 0.f;
        if (g < N) {
            size_t o = (size_t)mbase + (size_t)g * 64 + c;
            v = fl ? ((const float*)mout)[o] : bf2f(((const unsigned short*)mout)[o]);
        }
        ms[r][c] = v;
    }
    __syncthreads();

    float a4[4][4];
#pragma unroll
    for (int a = 0; a < 4; ++a)
#pragma unroll
        for (int b = 0; b < 4; ++b) a4[a][b] = 0.f;

#pragma unroll 8
    for (int k = 0; k < 64; ++k) {
        float4 w4 = *reinterpret_cast<const float4*>(&Ws[k][tx << 2]);
#pragma unroll
        for (int rr = 0; rr < 4; ++rr) {
            float xv = ms[ty + 16 * rr][k];
            a4[rr][0] += xv * w4.x;
            a4[rr][1] += xv * w4.y;
            a4[rr][2] += xv * w4.z;
            a4[rr][3] += xv * w4.w;
        }
    }
#pragma unroll
    for (int rr = 0; rr < 4; ++rr) {
        int g = row0 + ty + 16 * rr;
        if (g >= N) continue;
        size_t ob = (size_t)mbase + (size_t)g * 64 + (tx << 2);
        if (fl) {
            float4 o;
            o.x = fmaxf(a4[rr][0], 0.f); o.y = fmaxf(a4[rr][1], 0.f);
            o.z = fmaxf(a4[rr][2], 0.f); o.w = fmaxf(a4[rr][3], 0.f);
            *reinterpret_cast<float4*>(&((float*)mout)[ob]) = o;
        } else {
            ushort4 o;
            o.x = f2bf(fmaxf(a4[rr][0], 0.f)); o.y = f2bf(fmaxf(a4[rr][1], 0.f));
            o.z = f2bf(fmaxf(a4[rr][2], 0.f)); o.w = f2bf(fmaxf(a4[rr][3], 0.f));
            *reinterpret_cast<ushort4*>(&((unsigned short*)mout)[ob]) = o;
        }
    }
}

extern "C" void kernel_launch(void* const* d_in, const int* in_sizes, int n_in,
                              void* d_out, int out_size, void* d_ws, size_t ws_size,
                              hipStream_t stream)
{
    static const int Ns[5] = {50000, 150000, 100000, 40000, 10000};

    // ---- input pointer map (setup_inputs dict order) ----
    const void *x[5], *av[5], *cci[5], *Whbs[5], *Wagg[5];
    const int *ar[5], *ac[5];
    int nnzA[5];
    for (int r = 0; r < 5; ++r) {
        x[r]    = d_in[r * 7 + 0];
        ar[r]   = (const int*)d_in[r * 7 + 1];
        ac[r]   = (const int*)d_in[r * 7 + 2];
        av[r]   = d_in[r * 7 + 3];
        cci[r]  = d_in[r * 7 + 4];
        Whbs[r] = d_in[r * 7 + 5];
        Wagg[r] = d_in[r * 7 + 6];
        nnzA[r] = in_sizes[r * 7 + 3];
    }
    const int *it[4], *is[4];
    const void *iv[4], *Wsp[4], *Wtp[4];
    int nnzI[4];
    for (int k = 0; k < 4; ++k) {
        it[k]  = (const int*)d_in[35 + k * 5 + 0];
        is[k]  = (const int*)d_in[35 + k * 5 + 1];
        iv[k]  = d_in[35 + k * 5 + 2];
        Wsp[k] = d_in[35 + k * 5 + 3];
        Wtp[k] = d_in[35 + k * 5 + 4];
        nnzI[k] = in_sizes[35 + k * 5 + 2];
    }

    // ---- workspace: ONE f32 acc chunk + a 4B dtype flag at the top ----
    char* ws = (char*)d_ws;
    size_t flag_off = (ws_size >= 4096) ? ((ws_size - 4) & ~(size_t)3) : 0;
    int* flag = (int*)(ws + flag_off);
    float* acc = (float*)ws;
    // rows of f32 acc (256 B each) that fit below the flag, multiple of 64
    long long budget = (long long)((flag_off - 256) / 256);
    budget &= ~63LL;
    if (budget < 64) budget = 64;   // pathological ws: best effort

    probe_dtype<<<1, 64, 0, stream>>>((const unsigned short*)x[0], flag);

    dim3 b256(256);
    dim3 sb(64, 4);
    long long base = 0;   // element offset of this rank's chunk in d_out

    for (int r = 0; r < 5; ++r) {
        const int N = Ns[r];

        // phase table: {rows, cols, vals, xsrc, W, nnz, mode}
        struct Ph { const int* rw; const int* cl; const void* vl; const void* xs;
                    const void* W; int nnz; int mode; };
        Ph ph[3]; int np = 0;
        ph[np++] = { ar[r], ac[r], av[r], x[r], Whbs[r], nnzA[r], 0 };           // same-rank
        if (r < 4) ph[np++] = { it[r], is[r], iv[r], x[r + 1], Wsp[r], nnzI[r], 1 };      // down
        if (r > 0) ph[np++] = { is[r-1], it[r-1], iv[r-1], x[r - 1], Wtp[r-1], nnzI[r-1], 1 }; // up

        for (int p = 0; p < np; ++p) {
            for (long long r0 = 0; r0 < N; r0 += budget) {
                int rc = (int)((N - r0 < budget) ? (N - r0) : budget);
                hipMemsetAsync(acc, 0, (size_t)rc * 256, stream);
                scatter_x<<<(ph[p].nnz + 3) / 4, sb, 0, stream>>>(
                    ph[p].rw, ph[p].cl, ph[p].vl, ph[p].xs, flag,
                    acc, ph[p].nnz, (int)r0, (int)(r0 + rc));
                gemm_phase<<<(rc + 63) / 64, b256, 0, stream>>>(
                    acc, ph[p].W, cci[r], d_out, flag,
                    rc, r0, base, ph[p].mode);
            }
        }
        finalize<<<(N + 63) / 64, b256, 0, stream>>>(d_out, Wagg[r], flag, N, base);
        base += (long long)N * 64;
    }
}